// Round 18
// baseline (475.806 us; speedup 1.0000x reference)
//
#include <hip/hip_runtime.h>
#include <hip/hip_bf16.h>
#include <cstdint>

#define ASPACE(n) __attribute__((address_space(n)))

typedef short bf16x8 __attribute__((ext_vector_type(8)));
typedef float f32x4 __attribute__((ext_vector_type(4)));

__device__ __forceinline__ unsigned short f2bf(float f) {
  uint32_t u = __float_as_uint(f);
  u += 0x7fffu + ((u >> 16) & 1u);
  return (unsigned short)(u >> 16);
}
__device__ __forceinline__ float bf2f(unsigned short h) {
  return __uint_as_float(((uint32_t)h) << 16);
}

// pack 8 fp32 -> bf16x8 via v_cvt_pk_bf16_f32 (RNE, matches f2bf)
__device__ __forceinline__ bf16x8 cvt8(float4 a, float4 b) {
  union { uint32_t u[4]; bf16x8 v; } r;
  asm("v_cvt_pk_bf16_f32 %0, %1, %2" : "=v"(r.u[0]) : "v"(a.x), "v"(a.y));
  asm("v_cvt_pk_bf16_f32 %0, %1, %2" : "=v"(r.u[1]) : "v"(a.z), "v"(a.w));
  asm("v_cvt_pk_bf16_f32 %0, %1, %2" : "=v"(r.u[2]) : "v"(b.x), "v"(b.y));
  asm("v_cvt_pk_bf16_f32 %0, %1, %2" : "=v"(r.u[3]) : "v"(b.z), "v"(b.w));
  return r.v;
}

// ---------------- fp32 -> bf16 conversion (weights only) ----------------
__global__ __launch_bounds__(256) void conv_f32_bf16(const float4* __restrict__ src,
                                                     ushort4* __restrict__ dst, int n4) {
  int i = blockIdx.x * blockDim.x + threadIdx.x;
  int stride = gridDim.x * blockDim.x;
  for (; i < n4; i += stride) {
    float4 v = src[i];
    ushort4 o;
    o.x = f2bf(v.x); o.y = f2bf(v.y); o.z = f2bf(v.z); o.w = f2bf(v.w);
    dst[i] = o;
  }
}

__device__ __forceinline__ void gload16(const unsigned short* g, unsigned short* l) {
  __builtin_amdgcn_global_load_lds((const ASPACE(1) void*)g, (ASPACE(3) void*)l, 16, 0, 0);
}

// ---------------- QKV GEMM reading fp32 x directly ----------------
// r17 structure + r12-proven counted-vmcnt barrier discipline: A fp32 loads (t+2, issued
// AFTER B's gloads, order pinned by sched_barrier) ride across the raw s_barrier;
// vmcnt(4) retires only B's DMA; lgkmcnt(0) publishes the A ds_writes. Full unroll
// (K=384) so the A pending-register double-buffer is statically indexed (rule #20).
__global__ __launch_bounds__(256, 3) void gemm_qkv(const float* __restrict__ x,
                                                   const unsigned short* __restrict__ B,
                                                   unsigned short* __restrict__ C,
                                                   int M, int N, int K_unused) {
  const int K = 384;
  __shared__ unsigned short As[2][128 * 32];   // 16 KiB (bf16)
  __shared__ unsigned short Bs[2][192 * 32];   // 24 KiB

  const int tid  = threadIdx.x;
  const int lane = tid & 63;
  const int wave = tid >> 6;
  const int wr = wave >> 1;
  const int wc = wave & 1;

  const int nwg = gridDim.x;
  const int swz = (blockIdx.x & 7) * (nwg >> 3) + (blockIdx.x >> 3);
  const int ntn = N / 192;
  const int bn0 = (swz % ntn) * 192;
  const int bm0 = (swz / ntn) << 7;

  const unsigned short* Bbase = B + (size_t)bn0 * K;

  // A staging: 512 chunks (128 rows x 4 bf16-chunks); 2 per thread; swizzle (row>>1)&3.
  const float* gAf[2];
  int wAo[2];
#pragma unroll
  for (int i = 0; i < 2; ++i) {
    const int c = i * 256 + tid;
    const int r = c >> 2;
    const int gc = (c & 3) ^ ((r >> 1) & 3);
    gAf[i] = x + (size_t)(bm0 + r) * K + gc * 8;
    wAo[i] = c * 8;
  }
  // B staging (r7-verbatim)
  const unsigned short* gB[3];
  unsigned short* lB[3];
#pragma unroll
  for (int i = 0; i < 3; ++i) {
    const int c = i * 256 + tid;
    const int r = c >> 2;
    const int gc = (c & 3) ^ ((r >> 1) & 3);
    gB[i] = Bbase + (size_t)r * K + gc * 8;
    lB[i] = (unsigned short*)Bs + (i * 256 + wave * 64) * 8;
  }
  const int abufoff = 128 * 32;
  const int bbufoff = 192 * 32;

  const int fr = lane & 15;
  const int hi = lane >> 4;
  int afo[4], bfo[6];
#pragma unroll
  for (int m = 0; m < 4; ++m) {
    const int row = wr * 64 + m * 16 + fr;
    afo[m] = row * 32 + ((hi ^ ((row >> 1) & 3)) * 8);
  }
#pragma unroll
  for (int n = 0; n < 6; ++n) {
    const int row = wc * 96 + n * 16 + fr;
    bfo[n] = row * 32 + ((hi ^ ((row >> 1) & 3)) * 8);
  }

  f32x4 acc[4][6];
#pragma unroll
  for (int m = 0; m < 4; ++m)
#pragma unroll
    for (int n = 0; n < 6; ++n) {
      f32x4 z = {0.f, 0.f, 0.f, 0.f};
      acc[m][n] = z;
    }

  // pending A registers: p* = tile t+1 (to write this iter), q* = tile t+2 (in flight)
  float4 p0a, p0b, p1a, p1b, q0a, q0b, q1a, q1b;

  // ---- prologue ----
  // A(0) loads (oldest), then B(0) DMA, then A(1) loads; write A(0); publish.
  p0a = *(const float4*)(gAf[0]);     p0b = *(const float4*)(gAf[0] + 4);
  p1a = *(const float4*)(gAf[1]);     p1b = *(const float4*)(gAf[1] + 4);
  __builtin_amdgcn_sched_barrier(0);
#pragma unroll
  for (int i = 0; i < 3; ++i) gload16(gB[i], lB[i]);
  __builtin_amdgcn_sched_barrier(0);
  q0a = *(const float4*)(gAf[0] + 32); q0b = *(const float4*)(gAf[0] + 36);
  q1a = *(const float4*)(gAf[1] + 32); q1b = *(const float4*)(gAf[1] + 36);
  __builtin_amdgcn_sched_barrier(0);
  // cvt consumes A(0): compiler retires the 4 oldest loads; B(0)+A(1) remain
  *(bf16x8*)((unsigned short*)As + wAo[0]) = cvt8(p0a, p0b);
  *(bf16x8*)((unsigned short*)As + wAo[1]) = cvt8(p1a, p1b);
  asm volatile("s_waitcnt vmcnt(4) lgkmcnt(0)" ::: "memory");  // retire B(0); A(1) rides
  __builtin_amdgcn_s_barrier();
  __builtin_amdgcn_sched_barrier(0);
  p0a = q0a; p0b = q0b; p1a = q1a; p1b = q1b;   // p* = A(1)

#pragma unroll
  for (int t = 0; t < 12; ++t) {
    const int cur = t & 1;
    const int nb  = cur ^ 1;
    if (t < 11) {                       // B(t+1) DMA first (issue order pinned)
      const int k0 = (t + 1) << 5;
#pragma unroll
      for (int i = 0; i < 3; ++i) gload16(gB[i] + k0, lB[i] + nb * bbufoff);
    }
    __builtin_amdgcn_sched_barrier(0);
    if (t < 10) {                       // A(t+2) fp32 loads -> q* (ride 2 barriers)
      const int k0 = (t + 2) << 5;
      q0a = *(const float4*)(gAf[0] + k0); q0b = *(const float4*)(gAf[0] + k0 + 4);
      q1a = *(const float4*)(gAf[1] + k0); q1b = *(const float4*)(gAf[1] + k0 + 4);
    }
    __builtin_amdgcn_sched_barrier(0);
    // compute tile t
    {
      const unsigned short* Ab = (const unsigned short*)As + cur * abufoff;
      const unsigned short* Bb = (const unsigned short*)Bs + cur * bbufoff;
      bf16x8 af[4], bfv[6];
#pragma unroll
      for (int m = 0; m < 4; ++m) af[m] = *(const bf16x8*)(Ab + afo[m]);
#pragma unroll
      for (int n = 0; n < 6; ++n) bfv[n] = *(const bf16x8*)(Bb + bfo[n]);
#pragma unroll
      for (int m = 0; m < 4; ++m)
#pragma unroll
        for (int n = 0; n < 6; ++n)
          acc[m][n] = __builtin_amdgcn_mfma_f32_16x16x32_bf16(af[m], bfv[n], acc[m][n], 0, 0, 0);
    }
    if (t < 11) {
      // write A(t+1): cvt consumes p* -> compiler retires those loads (oldest)
      *(bf16x8*)((unsigned short*)As + nb * abufoff + wAo[0]) = cvt8(p0a, p0b);
      *(bf16x8*)((unsigned short*)As + nb * abufoff + wAo[1]) = cvt8(p1a, p1b);
      if (t < 10) {
        asm volatile("s_waitcnt vmcnt(4) lgkmcnt(0)" ::: "memory");  // retire B(t+1); A(t+2) rides
      } else {
        asm volatile("s_waitcnt vmcnt(0) lgkmcnt(0)" ::: "memory");  // last staging iter
      }
      __builtin_amdgcn_s_barrier();
      __builtin_amdgcn_sched_barrier(0);
      p0a = q0a; p0b = q0b; p1a = q1a; p1b = q1b;
    }
  }

  // epilogue -> head-major planes [col/48][row][48]
  const int rq = hi * 4;
#pragma unroll
  for (int m = 0; m < 4; ++m) {
#pragma unroll
    for (int n = 0; n < 6; ++n) {
      const int col = bn0 + wc * 96 + n * 16 + fr;
      const int pl = col / 48;
      const int d  = col - pl * 48;
      unsigned short* base = C + ((size_t)pl * M + bm0 + wr * 64 + m * 16 + rq) * 48 + d;
#pragma unroll
      for (int r = 0; r < 4; ++r)
        base[(size_t)r * 48] = f2bf(acc[m][n][r]);
    }
  }
}

// ---------------- FUSED windowed attention + proj GEMM (r16-verbatim) ----------------
#define MTOK 131072
#define ASTR 392
__global__ __launch_bounds__(512, 2) void fused_attn_proj(const unsigned short* __restrict__ qkv,
                                                          const unsigned short* __restrict__ Wp,
                                                          const float* __restrict__ bias,
                                                          float* __restrict__ out) {
  __shared__ unsigned short lds[50176 + 24576];   // attn[128][392] | Bs dbuf / p1 scratch
  unsigned short* attn = lds;
  unsigned short* BsS  = lds + 50176;

  const int tid = threadIdx.x, lane = tid & 63, wave = tid >> 6;
  const int nwg = gridDim.x;                       // 1024, %8==0
  const int swz = (blockIdx.x & 7) * (nwg >> 3) + (blockIdx.x >> 3);
  const int b = swz >> 7, g2 = swz & 127;
  const int yb = g2 >> 2, xb = g2 & 3;
  const int imgbase = b * 16384;

  const int lg = lane >> 4;
  const int lr = lane & 15;

  // ===== phase 1: attention; per-wave private scratch; no in-loop barriers =====
  {
    unsigned short* Vt = BsS + wave * 1536;        // [48][24]
    unsigned short* P  = Vt + 48 * 24;             // [16][24]
    const int gtok = imgbase + (yb * 4 + (lr >> 2)) * 128 + xb * 32 + wave * 4 + (lr & 3);

    for (int h = 0; h < 8; ++h) {
      const size_t qb = ((size_t)h * MTOK + gtok) * 48;
      const size_t kb = ((size_t)(8 + h) * MTOK + gtok) * 48;
      const size_t vb = ((size_t)(16 + h) * MTOK + gtok) * 48;

      bf16x8 aq0 = *(const bf16x8*)(qkv + qb + lg * 8);
      bf16x8 bk0 = *(const bf16x8*)(qkv + kb + lg * 8);
      bf16x8 aq1 = {0, 0, 0, 0, 0, 0, 0, 0};
      bf16x8 bk1 = {0, 0, 0, 0, 0, 0, 0, 0};
      if (lg < 2) {
        aq1 = *(const bf16x8*)(qkv + qb + 32 + lg * 8);
        bk1 = *(const bf16x8*)(qkv + kb + 32 + lg * 8);
      }
      {
        bf16x8 v = *(const bf16x8*)(qkv + vb + lg * 8);
#pragma unroll
        for (int i = 0; i < 8; ++i) Vt[(lg * 8 + i) * 24 + lr] = (unsigned short)v[i];
        if (lane < 32) {
          bf16x8 v2 = *(const bf16x8*)(qkv + vb + 32 + lg * 8);
#pragma unroll
          for (int i = 0; i < 8; ++i) Vt[((4 + lg) * 8 + i) * 24 + lr] = (unsigned short)v2[i];
        }
      }

      f32x4 s = {0.f, 0.f, 0.f, 0.f};
      s = __builtin_amdgcn_mfma_f32_16x16x32_bf16(aq0, bk0, s, 0, 0, 0);
      s = __builtin_amdgcn_mfma_f32_16x16x32_bf16(aq1, bk1, s, 0, 0, 0);

      const float scale = 0.14433756729740643f;    // 1/sqrt(48)
      float p[4];
#pragma unroll
      for (int r = 0; r < 4; ++r) {
        float xv = s[r] * scale;
        float m = xv;
        m = fmaxf(m, __shfl_xor(m, 1));
        m = fmaxf(m, __shfl_xor(m, 2));
        m = fmaxf(m, __shfl_xor(m, 4));
        m = fmaxf(m, __shfl_xor(m, 8));
        float e = __expf(xv - m);
        float tt = e;
        tt += __shfl_xor(tt, 1);
        tt += __shfl_xor(tt, 2);
        tt += __shfl_xor(tt, 4);
        tt += __shfl_xor(tt, 8);
        p[r] = e / tt;
      }
#pragma unroll
      for (int r = 0; r < 4; ++r) P[(lg * 4 + r) * 24 + lr] = f2bf(p[r]);

      bf16x8 ap = {0, 0, 0, 0, 0, 0, 0, 0};
      if (lg < 2) ap = *(const bf16x8*)(P + lr * 24 + lg * 8);

      f32x4 o[3];
#pragma unroll
      for (int c = 0; c < 3; ++c) {
        bf16x8 bv = {0, 0, 0, 0, 0, 0, 0, 0};
        if (lg < 2) bv = *(const bf16x8*)(Vt + (c * 16 + lr) * 24 + lg * 8);
        f32x4 z = {0.f, 0.f, 0.f, 0.f};
        o[c] = __builtin_amdgcn_mfma_f32_16x16x32_bf16(ap, bv, z, 0, 0, 0);
      }

#pragma unroll
      for (int r = 0; r < 4; ++r) {
        const int qi = lg * 4 + r;
        const int lq = (qi >> 2) * 32 + wave * 4 + (qi & 3);
#pragma unroll
        for (int c = 0; c < 3; ++c)
          attn[lq * ASTR + h * 48 + c * 16 + lr] = f2bf(o[c][r]);
      }
    }
  }
  __syncthreads();   // attn[] published; scratch reads done -> BsS free

  // ===== phase 2: proj GEMM; A = attn tile (LDS-resident), B = Wp dbuf =====
  const int fr = lane & 15;
  const int hi = lane >> 4;
  const int wr = wave >> 1;
  const int wc = wave & 1;

  const unsigned short* gB[3];
  unsigned short* lB[3];
#pragma unroll
  for (int i = 0; i < 3; ++i) {
    const int c = i * 512 + tid;
    const int r = c >> 2;
    const int gc = (c & 3) ^ ((r >> 1) & 3);
    gB[i] = Wp + (size_t)r * 384 + gc * 8;
    lB[i] = BsS + (i * 512 + wave * 64) * 8;
  }
  const int bbufoff = 384 * 32;

  int afo[2], bfo[12];
#pragma unroll
  for (int mf = 0; mf < 2; ++mf) {
    const int row = wr * 32 + mf * 16 + fr;
    afo[mf] = row * ASTR;
  }
#pragma unroll
  for (int nf = 0; nf < 12; ++nf) {
    const int row = wc * 192 + nf * 16 + fr;
    bfo[nf] = row * 32 + ((hi ^ ((row >> 1) & 3)) * 8);
  }

  f32x4 acc[2][12];
#pragma unroll
  for (int mf = 0; mf < 2; ++mf)
#pragma unroll
    for (int nf = 0; nf < 12; ++nf) {
      f32x4 z = {0.f, 0.f, 0.f, 0.f};
      acc[mf][nf] = z;
    }

#pragma unroll
  for (int i = 0; i < 3; ++i) gload16(gB[i], lB[i]);
  __syncthreads();

  int cur = 0;
  for (int t = 0; t < 12; ++t) {
    if (t + 1 < 12) {
      const int nb = cur ^ 1;
      const int k0 = (t + 1) << 5;
#pragma unroll
      for (int i = 0; i < 3; ++i) gload16(gB[i] + k0, lB[i] + nb * bbufoff);
    }
    {
      const unsigned short* Bb = BsS + cur * bbufoff;
      bf16x8 af[2], bfv[12];
#pragma unroll
      for (int mf = 0; mf < 2; ++mf)
        af[mf] = *(const bf16x8*)(attn + afo[mf] + t * 32 + hi * 8);
#pragma unroll
      for (int nf = 0; nf < 12; ++nf) bfv[nf] = *(const bf16x8*)(Bb + bfo[nf]);
#pragma unroll
      for (int mf = 0; mf < 2; ++mf)
#pragma unroll
        for (int nf = 0; nf < 12; ++nf)
          acc[mf][nf] = __builtin_amdgcn_mfma_f32_16x16x32_bf16(af[mf], bfv[nf], acc[mf][nf], 0, 0, 0);
    }
    __syncthreads();
    cur ^= 1;
  }

  const int rq = hi * 4;
#pragma unroll
  for (int mf = 0; mf < 2; ++mf) {
#pragma unroll
    for (int nf = 0; nf < 12; ++nf) {
      const int col = wc * 192 + nf * 16 + fr;
      const float bv = bias[col];
#pragma unroll
      for (int r = 0; r < 4; ++r) {
        const int l = wr * 32 + mf * 16 + rq + r;
        const int gtok = imgbase + (yb * 4 + (l >> 5)) * 128 + xb * 32 + (l & 31);
        out[(size_t)gtok * 384 + col] = acc[mf][nf][r] + bv;
      }
    }
  }
}

// ---------------- launch ----------------
extern "C" void kernel_launch(void* const* d_in, const int* in_sizes, int n_in,
                              void* d_out, int out_size, void* d_ws, size_t ws_size,
                              hipStream_t stream) {
  const float* x      = (const float*)d_in[0];
  const float* W_qkv  = (const float*)d_in[1];
  const float* W_proj = (const float*)d_in[2];
  const float* b_proj = (const float*)d_in[3];
  float* out = (float*)d_out;

  const int Bb = 8, Nn = 16384, Cc = 384;
  const int M = Bb * Nn;       // 131072
  const int threeC = 3 * Cc;   // 1152

  char* ws = (char*)d_ws;
  unsigned short* qkv_bf   = (unsigned short*)ws;                         // 24 planes [M][48]
  unsigned short* wqkv_bf  = (unsigned short*)(ws + (size_t)M * threeC * 2);
  unsigned short* wproj_bf = wqkv_bf + threeC * Cc;

  // weight conversions only (tiny)
  conv_f32_bf16<<<432, 256, 0, stream>>>((const float4*)W_qkv, (ushort4*)wqkv_bf,
                                         threeC * Cc / 4);
  conv_f32_bf16<<<144, 256, 0, stream>>>((const float4*)W_proj, (ushort4*)wproj_bf,
                                         Cc * Cc / 4);

  // qkv = bf16(x) @ W_qkv^T (fp32 x read directly; head-major planes): 1024 x 6 = 6144
  gemm_qkv<<<(M / 128) * (threeC / 192), 256, 0, stream>>>(x, wqkv_bf, qkv_bf,
                                                           M, threeC, Cc);

  // fused attention + proj: 1024 strip-blocks (%8==0)
  fused_attn_proj<<<M / 128, 512, 0, stream>>>(qkv_bf, wproj_bf, b_proj, out);
}

// Round 19
// 426.069 us; speedup vs baseline: 1.1167x; 1.1167x over previous
//
#include <hip/hip_runtime.h>
#include <hip/hip_bf16.h>
#include <cstdint>

#define ASPACE(n) __attribute__((address_space(n)))

typedef short bf16x8 __attribute__((ext_vector_type(8)));
typedef float f32x4 __attribute__((ext_vector_type(4)));

__device__ __forceinline__ unsigned short f2bf(float f) {
  uint32_t u = __float_as_uint(f);
  u += 0x7fffu + ((u >> 16) & 1u);
  return (unsigned short)(u >> 16);
}
__device__ __forceinline__ float bf2f(unsigned short h) {
  return __uint_as_float(((uint32_t)h) << 16);
}

// pack 8 fp32 -> bf16x8 via v_cvt_pk_bf16_f32 (RNE, matches f2bf)
__device__ __forceinline__ bf16x8 cvt8(float4 a, float4 b) {
  union { uint32_t u[4]; bf16x8 v; } r;
  asm("v_cvt_pk_bf16_f32 %0, %1, %2" : "=v"(r.u[0]) : "v"(a.x), "v"(a.y));
  asm("v_cvt_pk_bf16_f32 %0, %1, %2" : "=v"(r.u[1]) : "v"(a.z), "v"(a.w));
  asm("v_cvt_pk_bf16_f32 %0, %1, %2" : "=v"(r.u[2]) : "v"(b.x), "v"(b.y));
  asm("v_cvt_pk_bf16_f32 %0, %1, %2" : "=v"(r.u[3]) : "v"(b.z), "v"(b.w));
  return r.v;
}

// ---------------- fp32 -> bf16 conversion (weights only) ----------------
__global__ __launch_bounds__(256) void conv_f32_bf16(const float4* __restrict__ src,
                                                     ushort4* __restrict__ dst, int n4) {
  int i = blockIdx.x * blockDim.x + threadIdx.x;
  int stride = gridDim.x * blockDim.x;
  for (; i < n4; i += stride) {
    float4 v = src[i];
    ushort4 o;
    o.x = f2bf(v.x); o.y = f2bf(v.y); o.z = f2bf(v.z); o.w = f2bf(v.w);
    dst[i] = o;
  }
}

__device__ __forceinline__ void gload16(const unsigned short* g, unsigned short* l) {
  __builtin_amdgcn_global_load_lds((const ASPACE(1) void*)g, (ASPACE(3) void*)l, 16, 0, 0);
}

// ---------------- QKV GEMM reading fp32 x directly ----------------
// r18 counted-vmcnt schedule, with __launch_bounds__(256,2): the 2-deep A-prefetch
// (8 pending float4 = 32 VGPR) fits without scratch spill (r18's 256,3 cap spilled:
// WRITE_SIZE 295->506 MB). ILP (2-barrier-deep A loads, counted vmcnt) replaces TLP.
__global__ __launch_bounds__(256, 2) void gemm_qkv(const float* __restrict__ x,
                                                   const unsigned short* __restrict__ B,
                                                   unsigned short* __restrict__ C,
                                                   int M, int N, int K_unused) {
  const int K = 384;
  __shared__ unsigned short As[2][128 * 32];   // 16 KiB (bf16)
  __shared__ unsigned short Bs[2][192 * 32];   // 24 KiB

  const int tid  = threadIdx.x;
  const int lane = tid & 63;
  const int wave = tid >> 6;
  const int wr = wave >> 1;
  const int wc = wave & 1;

  const int nwg = gridDim.x;
  const int swz = (blockIdx.x & 7) * (nwg >> 3) + (blockIdx.x >> 3);
  const int ntn = N / 192;
  const int bn0 = (swz % ntn) * 192;
  const int bm0 = (swz / ntn) << 7;

  const unsigned short* Bbase = B + (size_t)bn0 * K;

  // A staging: 512 chunks (128 rows x 4 bf16-chunks); 2 per thread; swizzle (row>>1)&3.
  const float* gAf[2];
  int wAo[2];
#pragma unroll
  for (int i = 0; i < 2; ++i) {
    const int c = i * 256 + tid;
    const int r = c >> 2;
    const int gc = (c & 3) ^ ((r >> 1) & 3);
    gAf[i] = x + (size_t)(bm0 + r) * K + gc * 8;
    wAo[i] = c * 8;
  }
  // B staging (r7-verbatim)
  const unsigned short* gB[3];
  unsigned short* lB[3];
#pragma unroll
  for (int i = 0; i < 3; ++i) {
    const int c = i * 256 + tid;
    const int r = c >> 2;
    const int gc = (c & 3) ^ ((r >> 1) & 3);
    gB[i] = Bbase + (size_t)r * K + gc * 8;
    lB[i] = (unsigned short*)Bs + (i * 256 + wave * 64) * 8;
  }
  const int abufoff = 128 * 32;
  const int bbufoff = 192 * 32;

  const int fr = lane & 15;
  const int hi = lane >> 4;
  int afo[4], bfo[6];
#pragma unroll
  for (int m = 0; m < 4; ++m) {
    const int row = wr * 64 + m * 16 + fr;
    afo[m] = row * 32 + ((hi ^ ((row >> 1) & 3)) * 8);
  }
#pragma unroll
  for (int n = 0; n < 6; ++n) {
    const int row = wc * 96 + n * 16 + fr;
    bfo[n] = row * 32 + ((hi ^ ((row >> 1) & 3)) * 8);
  }

  f32x4 acc[4][6];
#pragma unroll
  for (int m = 0; m < 4; ++m)
#pragma unroll
    for (int n = 0; n < 6; ++n) {
      f32x4 z = {0.f, 0.f, 0.f, 0.f};
      acc[m][n] = z;
    }

  // pending A registers: p* = tile t+1 (written this iter), q* = tile t+2 (in flight)
  float4 p0a, p0b, p1a, p1b, q0a, q0b, q1a, q1b;

  // ---- prologue ----
  p0a = *(const float4*)(gAf[0]);     p0b = *(const float4*)(gAf[0] + 4);
  p1a = *(const float4*)(gAf[1]);     p1b = *(const float4*)(gAf[1] + 4);
  __builtin_amdgcn_sched_barrier(0);
#pragma unroll
  for (int i = 0; i < 3; ++i) gload16(gB[i], lB[i]);
  __builtin_amdgcn_sched_barrier(0);
  q0a = *(const float4*)(gAf[0] + 32); q0b = *(const float4*)(gAf[0] + 36);
  q1a = *(const float4*)(gAf[1] + 32); q1b = *(const float4*)(gAf[1] + 36);
  __builtin_amdgcn_sched_barrier(0);
  *(bf16x8*)((unsigned short*)As + wAo[0]) = cvt8(p0a, p0b);
  *(bf16x8*)((unsigned short*)As + wAo[1]) = cvt8(p1a, p1b);
  asm volatile("s_waitcnt vmcnt(4) lgkmcnt(0)" ::: "memory");  // retire B(0); A(1) rides
  __builtin_amdgcn_s_barrier();
  __builtin_amdgcn_sched_barrier(0);
  p0a = q0a; p0b = q0b; p1a = q1a; p1b = q1b;   // p* = A(1)

#pragma unroll
  for (int t = 0; t < 12; ++t) {
    const int cur = t & 1;
    const int nb  = cur ^ 1;
    if (t < 11) {                       // B(t+1) DMA first (issue order pinned)
      const int k0 = (t + 1) << 5;
#pragma unroll
      for (int i = 0; i < 3; ++i) gload16(gB[i] + k0, lB[i] + nb * bbufoff);
    }
    __builtin_amdgcn_sched_barrier(0);
    if (t < 10) {                       // A(t+2) fp32 loads -> q* (ride 2 barriers)
      const int k0 = (t + 2) << 5;
      q0a = *(const float4*)(gAf[0] + k0); q0b = *(const float4*)(gAf[0] + k0 + 4);
      q1a = *(const float4*)(gAf[1] + k0); q1b = *(const float4*)(gAf[1] + k0 + 4);
    }
    __builtin_amdgcn_sched_barrier(0);
    // compute tile t
    {
      const unsigned short* Ab = (const unsigned short*)As + cur * abufoff;
      const unsigned short* Bb = (const unsigned short*)Bs + cur * bbufoff;
      bf16x8 af[4], bfv[6];
#pragma unroll
      for (int m = 0; m < 4; ++m) af[m] = *(const bf16x8*)(Ab + afo[m]);
#pragma unroll
      for (int n = 0; n < 6; ++n) bfv[n] = *(const bf16x8*)(Bb + bfo[n]);
#pragma unroll
      for (int m = 0; m < 4; ++m)
#pragma unroll
        for (int n = 0; n < 6; ++n)
          acc[m][n] = __builtin_amdgcn_mfma_f32_16x16x32_bf16(af[m], bfv[n], acc[m][n], 0, 0, 0);
    }
    if (t < 11) {
      *(bf16x8*)((unsigned short*)As + nb * abufoff + wAo[0]) = cvt8(p0a, p0b);
      *(bf16x8*)((unsigned short*)As + nb * abufoff + wAo[1]) = cvt8(p1a, p1b);
      if (t < 10) {
        asm volatile("s_waitcnt vmcnt(4) lgkmcnt(0)" ::: "memory");  // retire B(t+1); A(t+2) rides
      } else {
        asm volatile("s_waitcnt vmcnt(0) lgkmcnt(0)" ::: "memory");
      }
      __builtin_amdgcn_s_barrier();
      __builtin_amdgcn_sched_barrier(0);
      p0a = q0a; p0b = q0b; p1a = q1a; p1b = q1b;
    }
  }

  // epilogue -> head-major planes [col/48][row][48]
  const int rq = hi * 4;
#pragma unroll
  for (int m = 0; m < 4; ++m) {
#pragma unroll
    for (int n = 0; n < 6; ++n) {
      const int col = bn0 + wc * 96 + n * 16 + fr;
      const int pl = col / 48;
      const int d  = col - pl * 48;
      unsigned short* base = C + ((size_t)pl * M + bm0 + wr * 64 + m * 16 + rq) * 48 + d;
#pragma unroll
      for (int r = 0; r < 4; ++r)
        base[(size_t)r * 48] = f2bf(acc[m][n][r]);
    }
  }
}

// ---------------- FUSED windowed attention + proj GEMM (r16-verbatim) ----------------
#define MTOK 131072
#define ASTR 392
__global__ __launch_bounds__(512, 2) void fused_attn_proj(const unsigned short* __restrict__ qkv,
                                                          const unsigned short* __restrict__ Wp,
                                                          const float* __restrict__ bias,
                                                          float* __restrict__ out) {
  __shared__ unsigned short lds[50176 + 24576];   // attn[128][392] | Bs dbuf / p1 scratch
  unsigned short* attn = lds;
  unsigned short* BsS  = lds + 50176;

  const int tid = threadIdx.x, lane = tid & 63, wave = tid >> 6;
  const int nwg = gridDim.x;                       // 1024, %8==0
  const int swz = (blockIdx.x & 7) * (nwg >> 3) + (blockIdx.x >> 3);
  const int b = swz >> 7, g2 = swz & 127;
  const int yb = g2 >> 2, xb = g2 & 3;
  const int imgbase = b * 16384;

  const int lg = lane >> 4;
  const int lr = lane & 15;

  // ===== phase 1: attention; per-wave private scratch; no in-loop barriers =====
  {
    unsigned short* Vt = BsS + wave * 1536;        // [48][24]
    unsigned short* P  = Vt + 48 * 24;             // [16][24]
    const int gtok = imgbase + (yb * 4 + (lr >> 2)) * 128 + xb * 32 + wave * 4 + (lr & 3);

    for (int h = 0; h < 8; ++h) {
      const size_t qb = ((size_t)h * MTOK + gtok) * 48;
      const size_t kb = ((size_t)(8 + h) * MTOK + gtok) * 48;
      const size_t vb = ((size_t)(16 + h) * MTOK + gtok) * 48;

      bf16x8 aq0 = *(const bf16x8*)(qkv + qb + lg * 8);
      bf16x8 bk0 = *(const bf16x8*)(qkv + kb + lg * 8);
      bf16x8 aq1 = {0, 0, 0, 0, 0, 0, 0, 0};
      bf16x8 bk1 = {0, 0, 0, 0, 0, 0, 0, 0};
      if (lg < 2) {
        aq1 = *(const bf16x8*)(qkv + qb + 32 + lg * 8);
        bk1 = *(const bf16x8*)(qkv + kb + 32 + lg * 8);
      }
      {
        bf16x8 v = *(const bf16x8*)(qkv + vb + lg * 8);
#pragma unroll
        for (int i = 0; i < 8; ++i) Vt[(lg * 8 + i) * 24 + lr] = (unsigned short)v[i];
        if (lane < 32) {
          bf16x8 v2 = *(const bf16x8*)(qkv + vb + 32 + lg * 8);
#pragma unroll
          for (int i = 0; i < 8; ++i) Vt[((4 + lg) * 8 + i) * 24 + lr] = (unsigned short)v2[i];
        }
      }

      f32x4 s = {0.f, 0.f, 0.f, 0.f};
      s = __builtin_amdgcn_mfma_f32_16x16x32_bf16(aq0, bk0, s, 0, 0, 0);
      s = __builtin_amdgcn_mfma_f32_16x16x32_bf16(aq1, bk1, s, 0, 0, 0);

      const float scale = 0.14433756729740643f;    // 1/sqrt(48)
      float p[4];
#pragma unroll
      for (int r = 0; r < 4; ++r) {
        float xv = s[r] * scale;
        float m = xv;
        m = fmaxf(m, __shfl_xor(m, 1));
        m = fmaxf(m, __shfl_xor(m, 2));
        m = fmaxf(m, __shfl_xor(m, 4));
        m = fmaxf(m, __shfl_xor(m, 8));
        float e = __expf(xv - m);
        float tt = e;
        tt += __shfl_xor(tt, 1);
        tt += __shfl_xor(tt, 2);
        tt += __shfl_xor(tt, 4);
        tt += __shfl_xor(tt, 8);
        p[r] = e / tt;
      }
#pragma unroll
      for (int r = 0; r < 4; ++r) P[(lg * 4 + r) * 24 + lr] = f2bf(p[r]);

      bf16x8 ap = {0, 0, 0, 0, 0, 0, 0, 0};
      if (lg < 2) ap = *(const bf16x8*)(P + lr * 24 + lg * 8);

      f32x4 o[3];
#pragma unroll
      for (int c = 0; c < 3; ++c) {
        bf16x8 bv = {0, 0, 0, 0, 0, 0, 0, 0};
        if (lg < 2) bv = *(const bf16x8*)(Vt + (c * 16 + lr) * 24 + lg * 8);
        f32x4 z = {0.f, 0.f, 0.f, 0.f};
        o[c] = __builtin_amdgcn_mfma_f32_16x16x32_bf16(ap, bv, z, 0, 0, 0);
      }

#pragma unroll
      for (int r = 0; r < 4; ++r) {
        const int qi = lg * 4 + r;
        const int lq = (qi >> 2) * 32 + wave * 4 + (qi & 3);
#pragma unroll
        for (int c = 0; c < 3; ++c)
          attn[lq * ASTR + h * 48 + c * 16 + lr] = f2bf(o[c][r]);
      }
    }
  }
  __syncthreads();   // attn[] published; scratch reads done -> BsS free

  // ===== phase 2: proj GEMM; A = attn tile (LDS-resident), B = Wp dbuf =====
  const int fr = lane & 15;
  const int hi = lane >> 4;
  const int wr = wave >> 1;
  const int wc = wave & 1;

  const unsigned short* gB[3];
  unsigned short* lB[3];
#pragma unroll
  for (int i = 0; i < 3; ++i) {
    const int c = i * 512 + tid;
    const int r = c >> 2;
    const int gc = (c & 3) ^ ((r >> 1) & 3);
    gB[i] = Wp + (size_t)r * 384 + gc * 8;
    lB[i] = BsS + (i * 512 + wave * 64) * 8;
  }
  const int bbufoff = 384 * 32;

  int afo[2], bfo[12];
#pragma unroll
  for (int mf = 0; mf < 2; ++mf) {
    const int row = wr * 32 + mf * 16 + fr;
    afo[mf] = row * ASTR;
  }
#pragma unroll
  for (int nf = 0; nf < 12; ++nf) {
    const int row = wc * 192 + nf * 16 + fr;
    bfo[nf] = row * 32 + ((hi ^ ((row >> 1) & 3)) * 8);
  }

  f32x4 acc[2][12];
#pragma unroll
  for (int mf = 0; mf < 2; ++mf)
#pragma unroll
    for (int nf = 0; nf < 12; ++nf) {
      f32x4 z = {0.f, 0.f, 0.f, 0.f};
      acc[mf][nf] = z;
    }

#pragma unroll
  for (int i = 0; i < 3; ++i) gload16(gB[i], lB[i]);
  __syncthreads();

  int cur = 0;
  for (int t = 0; t < 12; ++t) {
    if (t + 1 < 12) {
      const int nb = cur ^ 1;
      const int k0 = (t + 1) << 5;
#pragma unroll
      for (int i = 0; i < 3; ++i) gload16(gB[i] + k0, lB[i] + nb * bbufoff);
    }
    {
      const unsigned short* Bb = BsS + cur * bbufoff;
      bf16x8 af[2], bfv[12];
#pragma unroll
      for (int mf = 0; mf < 2; ++mf)
        af[mf] = *(const bf16x8*)(attn + afo[mf] + t * 32 + hi * 8);
#pragma unroll
      for (int nf = 0; nf < 12; ++nf) bfv[nf] = *(const bf16x8*)(Bb + bfo[nf]);
#pragma unroll
      for (int mf = 0; mf < 2; ++mf)
#pragma unroll
        for (int nf = 0; nf < 12; ++nf)
          acc[mf][nf] = __builtin_amdgcn_mfma_f32_16x16x32_bf16(af[mf], bfv[nf], acc[mf][nf], 0, 0, 0);
    }
    __syncthreads();
    cur ^= 1;
  }

  const int rq = hi * 4;
#pragma unroll
  for (int mf = 0; mf < 2; ++mf) {
#pragma unroll
    for (int nf = 0; nf < 12; ++nf) {
      const int col = wc * 192 + nf * 16 + fr;
      const float bv = bias[col];
#pragma unroll
      for (int r = 0; r < 4; ++r) {
        const int l = wr * 32 + mf * 16 + rq + r;
        const int gtok = imgbase + (yb * 4 + (l >> 5)) * 128 + xb * 32 + (l & 31);
        out[(size_t)gtok * 384 + col] = acc[mf][nf][r] + bv;
      }
    }
  }
}

// ---------------- launch ----------------
extern "C" void kernel_launch(void* const* d_in, const int* in_sizes, int n_in,
                              void* d_out, int out_size, void* d_ws, size_t ws_size,
                              hipStream_t stream) {
  const float* x      = (const float*)d_in[0];
  const float* W_qkv  = (const float*)d_in[1];
  const float* W_proj = (const float*)d_in[2];
  const float* b_proj = (const float*)d_in[3];
  float* out = (float*)d_out;

  const int Bb = 8, Nn = 16384, Cc = 384;
  const int M = Bb * Nn;       // 131072
  const int threeC = 3 * Cc;   // 1152

  char* ws = (char*)d_ws;
  unsigned short* qkv_bf   = (unsigned short*)ws;                         // 24 planes [M][48]
  unsigned short* wqkv_bf  = (unsigned short*)(ws + (size_t)M * threeC * 2);
  unsigned short* wproj_bf = wqkv_bf + threeC * Cc;

  // weight conversions only (tiny)
  conv_f32_bf16<<<432, 256, 0, stream>>>((const float4*)W_qkv, (ushort4*)wqkv_bf,
                                         threeC * Cc / 4);
  conv_f32_bf16<<<144, 256, 0, stream>>>((const float4*)W_proj, (ushort4*)wproj_bf,
                                         Cc * Cc / 4);

  // qkv = bf16(x) @ W_qkv^T (fp32 x read directly; head-major planes): 1024 x 6 = 6144
  gemm_qkv<<<(M / 128) * (threeC / 192), 256, 0, stream>>>(x, wqkv_bf, qkv_bf,
                                                           M, threeC, Cc);

  // fused attention + proj: 1024 strip-blocks (%8==0)
  fused_attn_proj<<<M / 128, 512, 0, stream>>>(qkv_bf, wproj_bf, b_proj, out);
}

// Round 20
// 387.834 us; speedup vs baseline: 1.2268x; 1.0986x over previous
//
#include <hip/hip_runtime.h>
#include <hip/hip_bf16.h>
#include <cstdint>

#define ASPACE(n) __attribute__((address_space(n)))

typedef short bf16x8 __attribute__((ext_vector_type(8)));
typedef float f32x4 __attribute__((ext_vector_type(4)));

__device__ __forceinline__ unsigned short f2bf(float f) {
  uint32_t u = __float_as_uint(f);
  u += 0x7fffu + ((u >> 16) & 1u);
  return (unsigned short)(u >> 16);
}
__device__ __forceinline__ float bf2f(unsigned short h) {
  return __uint_as_float(((uint32_t)h) << 16);
}

// pack 8 fp32 -> bf16x8 via v_cvt_pk_bf16_f32 (RNE, matches f2bf)
__device__ __forceinline__ bf16x8 cvt8(float4 a, float4 b) {
  union { uint32_t u[4]; bf16x8 v; } r;
  asm("v_cvt_pk_bf16_f32 %0, %1, %2" : "=v"(r.u[0]) : "v"(a.x), "v"(a.y));
  asm("v_cvt_pk_bf16_f32 %0, %1, %2" : "=v"(r.u[1]) : "v"(a.z), "v"(a.w));
  asm("v_cvt_pk_bf16_f32 %0, %1, %2" : "=v"(r.u[2]) : "v"(b.x), "v"(b.y));
  asm("v_cvt_pk_bf16_f32 %0, %1, %2" : "=v"(r.u[3]) : "v"(b.z), "v"(b.w));
  return r.v;
}

// ---------------- fp32 -> bf16 conversion (weights only) ----------------
__global__ __launch_bounds__(256) void conv_f32_bf16(const float4* __restrict__ src,
                                                     ushort4* __restrict__ dst, int n4) {
  int i = blockIdx.x * blockDim.x + threadIdx.x;
  int stride = gridDim.x * blockDim.x;
  for (; i < n4; i += stride) {
    float4 v = src[i];
    ushort4 o;
    o.x = f2bf(v.x); o.y = f2bf(v.y); o.z = f2bf(v.z); o.w = f2bf(v.w);
    dst[i] = o;
  }
}

__device__ __forceinline__ void gload16(const unsigned short* g, unsigned short* l) {
  __builtin_amdgcn_global_load_lds((const ASPACE(1) void*)g, (ASPACE(3) void*)l, 16, 0, 0);
}

// ---------------- QKV GEMM reading fp32 x directly (r17-verbatim, proven 244 us) -------
// 2-phase drain-0 loop at 3 blocks/CU (TLP > ILP for this kernel: r18/r19 counted-vmcnt
// at 2 blocks/CU measured 282-328 us vs this structure's 244).
__global__ __launch_bounds__(256, 3) void gemm_qkv(const float* __restrict__ x,
                                                   const unsigned short* __restrict__ B,
                                                   unsigned short* __restrict__ C,
                                                   int M, int N, int K) {
  __shared__ unsigned short As[2][128 * 32];   // 16 KiB (bf16)
  __shared__ unsigned short Bs[2][192 * 32];   // 24 KiB

  const int tid  = threadIdx.x;
  const int lane = tid & 63;
  const int wave = tid >> 6;
  const int wr = wave >> 1;
  const int wc = wave & 1;

  const int nwg = gridDim.x;
  const int swz = (blockIdx.x & 7) * (nwg >> 3) + (blockIdx.x >> 3);
  const int ntn = N / 192;
  const int bn0 = (swz % ntn) * 192;
  const int bm0 = (swz / ntn) << 7;

  const unsigned short* Bbase = B + (size_t)bn0 * K;

  // A staging: 512 chunks (128 rows x 4 bf16-chunks); 2 per thread; swizzle (row>>1)&3.
  const float* gAf[2];
  int wAo[2];
#pragma unroll
  for (int i = 0; i < 2; ++i) {
    const int c = i * 256 + tid;
    const int r = c >> 2;
    const int gc = (c & 3) ^ ((r >> 1) & 3);
    gAf[i] = x + (size_t)(bm0 + r) * K + gc * 8;
    wAo[i] = c * 8;
  }
  // B staging (r7-verbatim)
  const unsigned short* gB[3];
  unsigned short* lB[3];
#pragma unroll
  for (int i = 0; i < 3; ++i) {
    const int c = i * 256 + tid;
    const int r = c >> 2;
    const int gc = (c & 3) ^ ((r >> 1) & 3);
    gB[i] = Bbase + (size_t)r * K + gc * 8;
    lB[i] = (unsigned short*)Bs + (i * 256 + wave * 64) * 8;
  }
  const int abufoff = 128 * 32;
  const int bbufoff = 192 * 32;

  const int fr = lane & 15;
  const int hi = lane >> 4;
  int afo[4], bfo[6];
#pragma unroll
  for (int m = 0; m < 4; ++m) {
    const int row = wr * 64 + m * 16 + fr;
    afo[m] = row * 32 + ((hi ^ ((row >> 1) & 3)) * 8);
  }
#pragma unroll
  for (int n = 0; n < 6; ++n) {
    const int row = wc * 96 + n * 16 + fr;
    bfo[n] = row * 32 + ((hi ^ ((row >> 1) & 3)) * 8);
  }

  f32x4 acc[4][6];
#pragma unroll
  for (int m = 0; m < 4; ++m)
#pragma unroll
    for (int n = 0; n < 6; ++n) {
      f32x4 z = {0.f, 0.f, 0.f, 0.f};
      acc[m][n] = z;
    }

  const int NT = K >> 5;          // 12

  // prologue: tile 0
  float4 a0[2], a1[2];
#pragma unroll
  for (int i = 0; i < 2; ++i) { a0[i] = *(const float4*)(gAf[i]); a1[i] = *(const float4*)(gAf[i] + 4); }
#pragma unroll
  for (int i = 0; i < 3; ++i) gload16(gB[i], lB[i]);
#pragma unroll
  for (int i = 0; i < 2; ++i)
    *(bf16x8*)((unsigned short*)As + wAo[i]) = cvt8(a0[i], a1[i]);
  __syncthreads();

  int cur = 0;
  for (int t = 0; t < NT; ++t) {
    const int nb = cur ^ 1;
    if (t + 1 < NT) {            // issue next-tile loads first (land under compute)
      const int k0 = (t + 1) << 5;
#pragma unroll
      for (int i = 0; i < 2; ++i) { a0[i] = *(const float4*)(gAf[i] + k0); a1[i] = *(const float4*)(gAf[i] + k0 + 4); }
#pragma unroll
      for (int i = 0; i < 3; ++i) gload16(gB[i] + k0, lB[i] + nb * bbufoff);
    }
    // compute tile t
    {
      const unsigned short* Ab = (const unsigned short*)As + cur * abufoff;
      const unsigned short* Bb = (const unsigned short*)Bs + cur * bbufoff;
      bf16x8 af[4], bfv[6];
#pragma unroll
      for (int m = 0; m < 4; ++m) af[m] = *(const bf16x8*)(Ab + afo[m]);
#pragma unroll
      for (int n = 0; n < 6; ++n) bfv[n] = *(const bf16x8*)(Bb + bfo[n]);
#pragma unroll
      for (int m = 0; m < 4; ++m)
#pragma unroll
        for (int n = 0; n < 6; ++n)
          acc[m][n] = __builtin_amdgcn_mfma_f32_16x16x32_bf16(af[m], bfv[n], acc[m][n], 0, 0, 0);
    }
    if (t + 1 < NT) {            // A(t+1): cvt in-reg, ds_write into buf nb
#pragma unroll
      for (int i = 0; i < 2; ++i)
        *(bf16x8*)((unsigned short*)As + nb * abufoff + wAo[i]) = cvt8(a0[i], a1[i]);
    }
    __syncthreads();             // drains B DMA + A ds_writes; buf nb complete
    cur ^= 1;
  }

  // epilogue -> head-major planes [col/48][row][48]
  const int rq = hi * 4;
#pragma unroll
  for (int m = 0; m < 4; ++m) {
#pragma unroll
    for (int n = 0; n < 6; ++n) {
      const int col = bn0 + wc * 96 + n * 16 + fr;
      const int pl = col / 48;
      const int d  = col - pl * 48;
      unsigned short* base = C + ((size_t)pl * M + bm0 + wr * 64 + m * 16 + rq) * 48 + d;
#pragma unroll
      for (int r = 0; r < 4; ++r)
        base[(size_t)r * 48] = f2bf(acc[m][n][r]);
    }
  }
}

// ---------------- FUSED windowed attention + proj GEMM ----------------
// r16 structure + T5 s_setprio(1) around phase-1 MFMA clusters (waves free-run in
// phase 1 -> role diversity -> setprio pays per m191; phase 2 is barrier-locked
// GEMM where m190 showed setprio null, so left unwrapped).
#define MTOK 131072
#define ASTR 392
__global__ __launch_bounds__(512, 2) void fused_attn_proj(const unsigned short* __restrict__ qkv,
                                                          const unsigned short* __restrict__ Wp,
                                                          const float* __restrict__ bias,
                                                          float* __restrict__ out) {
  __shared__ unsigned short lds[50176 + 24576];   // attn[128][392] | Bs dbuf / p1 scratch
  unsigned short* attn = lds;
  unsigned short* BsS  = lds + 50176;

  const int tid = threadIdx.x, lane = tid & 63, wave = tid >> 6;
  const int nwg = gridDim.x;                       // 1024, %8==0
  const int swz = (blockIdx.x & 7) * (nwg >> 3) + (blockIdx.x >> 3);
  const int b = swz >> 7, g2 = swz & 127;
  const int yb = g2 >> 2, xb = g2 & 3;
  const int imgbase = b * 16384;

  const int lg = lane >> 4;
  const int lr = lane & 15;

  // ===== phase 1: attention; per-wave private scratch; no in-loop barriers =====
  {
    unsigned short* Vt = BsS + wave * 1536;        // [48][24]
    unsigned short* P  = Vt + 48 * 24;             // [16][24]
    const int gtok = imgbase + (yb * 4 + (lr >> 2)) * 128 + xb * 32 + wave * 4 + (lr & 3);

    for (int h = 0; h < 8; ++h) {
      const size_t qb = ((size_t)h * MTOK + gtok) * 48;
      const size_t kb = ((size_t)(8 + h) * MTOK + gtok) * 48;
      const size_t vb = ((size_t)(16 + h) * MTOK + gtok) * 48;

      bf16x8 aq0 = *(const bf16x8*)(qkv + qb + lg * 8);
      bf16x8 bk0 = *(const bf16x8*)(qkv + kb + lg * 8);
      bf16x8 aq1 = {0, 0, 0, 0, 0, 0, 0, 0};
      bf16x8 bk1 = {0, 0, 0, 0, 0, 0, 0, 0};
      if (lg < 2) {
        aq1 = *(const bf16x8*)(qkv + qb + 32 + lg * 8);
        bk1 = *(const bf16x8*)(qkv + kb + 32 + lg * 8);
      }
      {
        bf16x8 v = *(const bf16x8*)(qkv + vb + lg * 8);
#pragma unroll
        for (int i = 0; i < 8; ++i) Vt[(lg * 8 + i) * 24 + lr] = (unsigned short)v[i];
        if (lane < 32) {
          bf16x8 v2 = *(const bf16x8*)(qkv + vb + 32 + lg * 8);
#pragma unroll
          for (int i = 0; i < 8; ++i) Vt[((4 + lg) * 8 + i) * 24 + lr] = (unsigned short)v2[i];
        }
      }

      __builtin_amdgcn_s_setprio(1);
      f32x4 s = {0.f, 0.f, 0.f, 0.f};
      s = __builtin_amdgcn_mfma_f32_16x16x32_bf16(aq0, bk0, s, 0, 0, 0);
      s = __builtin_amdgcn_mfma_f32_16x16x32_bf16(aq1, bk1, s, 0, 0, 0);
      __builtin_amdgcn_s_setprio(0);

      const float scale = 0.14433756729740643f;    // 1/sqrt(48)
      float p[4];
#pragma unroll
      for (int r = 0; r < 4; ++r) {
        float xv = s[r] * scale;
        float m = xv;
        m = fmaxf(m, __shfl_xor(m, 1));
        m = fmaxf(m, __shfl_xor(m, 2));
        m = fmaxf(m, __shfl_xor(m, 4));
        m = fmaxf(m, __shfl_xor(m, 8));
        float e = __expf(xv - m);
        float tt = e;
        tt += __shfl_xor(tt, 1);
        tt += __shfl_xor(tt, 2);
        tt += __shfl_xor(tt, 4);
        tt += __shfl_xor(tt, 8);
        p[r] = e / tt;
      }
#pragma unroll
      for (int r = 0; r < 4; ++r) P[(lg * 4 + r) * 24 + lr] = f2bf(p[r]);

      bf16x8 ap = {0, 0, 0, 0, 0, 0, 0, 0};
      if (lg < 2) ap = *(const bf16x8*)(P + lr * 24 + lg * 8);

      f32x4 o[3];
      __builtin_amdgcn_s_setprio(1);
#pragma unroll
      for (int c = 0; c < 3; ++c) {
        bf16x8 bv = {0, 0, 0, 0, 0, 0, 0, 0};
        if (lg < 2) bv = *(const bf16x8*)(Vt + (c * 16 + lr) * 24 + lg * 8);
        f32x4 z = {0.f, 0.f, 0.f, 0.f};
        o[c] = __builtin_amdgcn_mfma_f32_16x16x32_bf16(ap, bv, z, 0, 0, 0);
      }
      __builtin_amdgcn_s_setprio(0);

#pragma unroll
      for (int r = 0; r < 4; ++r) {
        const int qi = lg * 4 + r;
        const int lq = (qi >> 2) * 32 + wave * 4 + (qi & 3);
#pragma unroll
        for (int c = 0; c < 3; ++c)
          attn[lq * ASTR + h * 48 + c * 16 + lr] = f2bf(o[c][r]);
      }
    }
  }
  __syncthreads();   // attn[] published; scratch reads done -> BsS free

  // ===== phase 2: proj GEMM; A = attn tile (LDS-resident), B = Wp dbuf =====
  const int fr = lane & 15;
  const int hi = lane >> 4;
  const int wr = wave >> 1;
  const int wc = wave & 1;

  const unsigned short* gB[3];
  unsigned short* lB[3];
#pragma unroll
  for (int i = 0; i < 3; ++i) {
    const int c = i * 512 + tid;
    const int r = c >> 2;
    const int gc = (c & 3) ^ ((r >> 1) & 3);
    gB[i] = Wp + (size_t)r * 384 + gc * 8;
    lB[i] = BsS + (i * 512 + wave * 64) * 8;
  }
  const int bbufoff = 384 * 32;

  int afo[2], bfo[12];
#pragma unroll
  for (int mf = 0; mf < 2; ++mf) {
    const int row = wr * 32 + mf * 16 + fr;
    afo[mf] = row * ASTR;
  }
#pragma unroll
  for (int nf = 0; nf < 12; ++nf) {
    const int row = wc * 192 + nf * 16 + fr;
    bfo[nf] = row * 32 + ((hi ^ ((row >> 1) & 3)) * 8);
  }

  f32x4 acc[2][12];
#pragma unroll
  for (int mf = 0; mf < 2; ++mf)
#pragma unroll
    for (int nf = 0; nf < 12; ++nf) {
      f32x4 z = {0.f, 0.f, 0.f, 0.f};
      acc[mf][nf] = z;
    }

#pragma unroll
  for (int i = 0; i < 3; ++i) gload16(gB[i], lB[i]);
  __syncthreads();

  int cur = 0;
  for (int t = 0; t < 12; ++t) {
    if (t + 1 < 12) {
      const int nb = cur ^ 1;
      const int k0 = (t + 1) << 5;
#pragma unroll
      for (int i = 0; i < 3; ++i) gload16(gB[i] + k0, lB[i] + nb * bbufoff);
    }
    {
      const unsigned short* Bb = BsS + cur * bbufoff;
      bf16x8 af[2], bfv[12];
#pragma unroll
      for (int mf = 0; mf < 2; ++mf)
        af[mf] = *(const bf16x8*)(attn + afo[mf] + t * 32 + hi * 8);
#pragma unroll
      for (int nf = 0; nf < 12; ++nf) bfv[nf] = *(const bf16x8*)(Bb + bfo[nf]);
#pragma unroll
      for (int mf = 0; mf < 2; ++mf)
#pragma unroll
        for (int nf = 0; nf < 12; ++nf)
          acc[mf][nf] = __builtin_amdgcn_mfma_f32_16x16x32_bf16(af[mf], bfv[nf], acc[mf][nf], 0, 0, 0);
    }
    __syncthreads();
    cur ^= 1;
  }

  const int rq = hi * 4;
#pragma unroll
  for (int mf = 0; mf < 2; ++mf) {
#pragma unroll
    for (int nf = 0; nf < 12; ++nf) {
      const int col = wc * 192 + nf * 16 + fr;
      const float bv = bias[col];
#pragma unroll
      for (int r = 0; r < 4; ++r) {
        const int l = wr * 32 + mf * 16 + rq + r;
        const int gtok = imgbase + (yb * 4 + (l >> 5)) * 128 + xb * 32 + (l & 31);
        out[(size_t)gtok * 384 + col] = acc[mf][nf][r] + bv;
      }
    }
  }
}

// ---------------- launch ----------------
extern "C" void kernel_launch(void* const* d_in, const int* in_sizes, int n_in,
                              void* d_out, int out_size, void* d_ws, size_t ws_size,
                              hipStream_t stream) {
  const float* x      = (const float*)d_in[0];
  const float* W_qkv  = (const float*)d_in[1];
  const float* W_proj = (const float*)d_in[2];
  const float* b_proj = (const float*)d_in[3];
  float* out = (float*)d_out;

  const int Bb = 8, Nn = 16384, Cc = 384;
  const int M = Bb * Nn;       // 131072
  const int threeC = 3 * Cc;   // 1152

  char* ws = (char*)d_ws;
  unsigned short* qkv_bf   = (unsigned short*)ws;                         // 24 planes [M][48]
  unsigned short* wqkv_bf  = (unsigned short*)(ws + (size_t)M * threeC * 2);
  unsigned short* wproj_bf = wqkv_bf + threeC * Cc;

  // weight conversions only (tiny)
  conv_f32_bf16<<<432, 256, 0, stream>>>((const float4*)W_qkv, (ushort4*)wqkv_bf,
                                         threeC * Cc / 4);
  conv_f32_bf16<<<144, 256, 0, stream>>>((const float4*)W_proj, (ushort4*)wproj_bf,
                                         Cc * Cc / 4);

  // qkv = bf16(x) @ W_qkv^T (fp32 x read directly; head-major planes): 1024 x 6 = 6144
  gemm_qkv<<<(M / 128) * (threeC / 192), 256, 0, stream>>>(x, wqkv_bf, qkv_bf,
                                                           M, threeC, Cc);

  // fused attention + proj: 1024 strip-blocks (%8==0)
  fused_attn_proj<<<M / 128, 512, 0, stream>>>(qkv_bf, wproj_bf, b_proj, out);
}